// Round 1
// baseline (330.002 us; speedup 1.0000x reference)
//
#include <hip/hip_runtime.h>

#define NN 50000
#define NE 1600000
#define NB 98          // buckets = ceil(NN/512)
#define BSH 9          // bucket = dst >> 9
#define BCAP 17408     // per-bucket capacity: mean 16384 + 8 sigma

// workspace layout (units of 4B)
#define OFF_H1    0          // bf16 [NN][128] = 3.2M u
#define OFF_AGG1  3200000    // f32  [NN][128] = 6.4M u (UNUSED after gf1 fusion)
#define OFF_HW2   9600000    // bf16 [NN][32]  = 0.8M u
#define OFF_AGG2  10400000   // f32  [NN][32]  = 1.6M u
#define OFF_DINV  12000000   // [NN] f32
#define OFF_ROWS  12050000   // [NN+1] int
#define OFF_GCNT  12101000   // [NB] int
#define OFF_GBASE 12101200   // [NB+1] int
#define OFF_CSRC  12102000   // [NE] int
#define OFF_BIN   13702000   // uint2[NB*BCAP] = 3,411,968 u
// total: 17,113,968 * 4B = 68.5 MB

__device__ __forceinline__ unsigned short f2b(float f) {
    unsigned u = __float_as_uint(f);
    u += 0x7fffu + ((u >> 16) & 1u);
    return (unsigned short)(u >> 16);
}
__device__ __forceinline__ float b2f(unsigned short h) {
    return __uint_as_float((unsigned)h << 16);
}

// Pass A: bin edges into 98 dst-buckets. Per-edge atomics are LDS-only;
// one global atomic per block-bucket (25K total).
__global__ __launch_bounds__(256) void k_binA(const int* __restrict__ ei,
                                              int* __restrict__ gcount,
                                              uint2* __restrict__ binned) {
    __shared__ int hist[NB];
    const int t = threadIdx.x;
    if (t < NB) hist[t] = 0;
    __syncthreads();
    const int e0 = blockIdx.x * (NE / 256);      // 6250 edges/block, exact
    const int e1 = e0 + (NE / 256);
    for (int e = e0 + t; e < e1; e += 256)
        atomicAdd(&hist[ei[NE + e] >> BSH], 1);
    __syncthreads();
    if (t < NB) {
        const int v = hist[t];
        hist[t] = atomicAdd(&gcount[t], v);      // becomes global cursor
    }
    __syncthreads();
    for (int e = e0 + t; e < e1; e += 256) {
        const int s = ei[e], d = ei[NE + e];
        const int b = d >> BSH;
        const int pos = atomicAdd(&hist[b], 1);
        binned[(size_t)b * BCAP + pos] = make_uint2((unsigned)s, (unsigned)d);
    }
}

// exclusive scan of gcount[98] -> gbase
__global__ __launch_bounds__(128) void k_base(const int* __restrict__ gcount,
                                              int* __restrict__ gbase) {
    __shared__ int s[128];
    const int t = threadIdx.x;
    const int v = (t < NB) ? gcount[t] : 0;
    s[t] = v;
    __syncthreads();
    #pragma unroll
    for (int off = 1; off < 128; off <<= 1) {
        const int x = (t >= off) ? s[t - off] : 0;
        __syncthreads();
        s[t] += x;
        __syncthreads();
    }
    if (t < NB) gbase[t] = s[t] - v;
    if (t == NB - 1) gbase[NB] = s[t];
}

// Pass B: one block per bucket. Per-node degree (LDS hist) -> dinv, rows;
// LDS scan -> offsets; scatter csrc into block-exclusive 64KB window.
__global__ __launch_bounds__(256) void k_binB(const int* __restrict__ gcount,
                                              const int* __restrict__ gbase,
                                              const uint2* __restrict__ binned,
                                              int* __restrict__ rows,
                                              float* __restrict__ dinv,
                                              int* __restrict__ csrc) {
    __shared__ int deg[512];
    __shared__ int off[512];
    __shared__ int partial[256];
    const int b = blockIdx.x, t = threadIdx.x;
    const int n0 = b << BSH;
    const int nloc = (NN - n0 < 512) ? (NN - n0) : 512;
    const int cnt = gcount[b];
    const int obase = gbase[b];
    const uint2* eb = binned + (size_t)b * BCAP;
    deg[t] = 0;
    deg[t + 256] = 0;
    __syncthreads();
    for (int i = t; i < cnt; i += 256) atomicAdd(&deg[eb[i].y & 511], 1);
    __syncthreads();
    const int s0 = deg[2 * t], s1 = deg[2 * t + 1];
    partial[t] = s0 + s1;
    __syncthreads();
    #pragma unroll
    for (int o = 1; o < 256; o <<= 1) {
        const int x = (t >= o) ? partial[t - o] : 0;
        __syncthreads();
        partial[t] += x;
        __syncthreads();
    }
    const int ep = partial[t] - (s0 + s1);
    off[2 * t] = ep;
    off[2 * t + 1] = ep + s0;
    __syncthreads();
    for (int i = t; i < nloc; i += 256) {
        rows[n0 + i] = obase + off[i];
        dinv[n0 + i] = rsqrtf((float)deg[i] + 1.0f);
    }
    if (b == NB - 1 && t == 0) rows[NN] = NE;
    __syncthreads();                 // rows reads of off[] done before cursor reuse
    for (int i = t; i < cnt; i += 256) {
        const uint2 r = eb[i];
        const int local = atomicAdd(&off[r.y & 511], 1);
        csrc[obase + local] = (int)r.x;
    }
}

// h1[n][c] = sum_k x[k][n] * W1[k][c]; output bf16
__global__ __launch_bounds__(256) void k_gemm1(const float* __restrict__ x,
                                               const float* __restrict__ W1,
                                               unsigned short* __restrict__ h1b) {
    __shared__ float xs[128][64];
    __shared__ float wsh[128][64];
    const int t = threadIdx.x;
    const int n0 = blockIdx.x * 64, c0 = blockIdx.y * 64;
    {
        const int col = t & 63, r0 = t >> 6;
        #pragma unroll
        for (int i = 0; i < 32; ++i) {
            const int r = r0 + 4 * i;
            const int n = n0 + col;
            xs[r][col]  = (n < NN) ? x[(size_t)r * NN + n] : 0.f;
            wsh[r][col] = W1[r * 128 + c0 + col];
        }
    }
    __syncthreads();
    const int nr = (t & 15) * 4, cg = (t >> 4) * 4;
    float acc[4][4];
    #pragma unroll
    for (int i = 0; i < 4; ++i)
        #pragma unroll
        for (int j = 0; j < 4; ++j) acc[i][j] = 0.f;
    #pragma unroll 8
    for (int k = 0; k < 128; ++k) {
        const float4 xv = *(const float4*)&xs[k][nr];
        const float4 wv = *(const float4*)&wsh[k][cg];
        const float xa[4] = {xv.x, xv.y, xv.z, xv.w};
        const float wa[4] = {wv.x, wv.y, wv.z, wv.w};
        #pragma unroll
        for (int i = 0; i < 4; ++i)
            #pragma unroll
            for (int j = 0; j < 4; ++j) acc[i][j] = fmaf(xa[i], wa[j], acc[i][j]);
    }
    #pragma unroll
    for (int i = 0; i < 4; ++i) {
        const int n = n0 + nr + i;
        if (n < NN) {
            ushort4 pk;
            pk.x = f2b(acc[i][0]); pk.y = f2b(acc[i][1]);
            pk.z = f2b(acc[i][2]); pk.w = f2b(acc[i][3]);
            *(ushort4*)&h1b[(size_t)n * 128 + c0 + cg] = pk;
        }
    }
}

// FUSED gather1 + fuse1: block = 4 waves, 32 dst nodes.
// Phase 1 (per wave, 8 nodes sequential): agg over neighbors in registers
//   (4-edge unroll, 4 outstanding 256B row loads), + self-loop + b1 + relu,
//   write 128-wide activation row to LDS.
// Phase 2 (block GEMM): [32x128] @ W2[128x32] -> hw2b (bf16).
// agg1 round-trip (25.6MB write + 25.6MB read) eliminated.
__global__ __launch_bounds__(256) void k_gf1(const int* __restrict__ rows,
                                             const int* __restrict__ csrc,
                                             const float* __restrict__ dinv,
                                             const unsigned short* __restrict__ h1b,
                                             const float* __restrict__ b1,
                                             const float* __restrict__ W2,
                                             unsigned short* __restrict__ hw2b) {
    __shared__ float hs[32][132];
    __shared__ float w2s[128 * 32];
    const int t = threadIdx.x;
    const int n0 = blockIdx.x * 32;
    #pragma unroll
    for (int i = 0; i < 16; ++i) w2s[t + 256 * i] = W2[t + 256 * i];
    const int wid = t >> 6, lane = t & 63;
    const float2 bb = *(const float2*)&b1[lane * 2];
    #pragma unroll 1
    for (int i = 0; i < 8; ++i) {
        const int nl = wid + 4 * i;          // 0..31, waves interleaved
        const int n = n0 + nl;
        float vx = 0.f, vy = 0.f;
        if (n < NN) {
            const int beg = rows[n], end = rows[n + 1];
            const float dn = dinv[n];
            float2 a0 = make_float2(0.f, 0.f), a1 = make_float2(0.f, 0.f);
            float2 a2 = make_float2(0.f, 0.f), a3 = make_float2(0.f, 0.f);
            int p = beg;
            for (; p + 4 <= end; p += 4) {
                const int s0 = csrc[p], s1 = csrc[p + 1];
                const int s2 = csrc[p + 2], s3 = csrc[p + 3];
                const unsigned u0 = *(const unsigned*)&h1b[(size_t)s0 * 128 + lane * 2];
                const unsigned u1 = *(const unsigned*)&h1b[(size_t)s1 * 128 + lane * 2];
                const unsigned u2 = *(const unsigned*)&h1b[(size_t)s2 * 128 + lane * 2];
                const unsigned u3 = *(const unsigned*)&h1b[(size_t)s3 * 128 + lane * 2];
                const float w0 = dinv[s0] * dn, w1 = dinv[s1] * dn;
                const float w2v = dinv[s2] * dn, w3 = dinv[s3] * dn;
                a0.x = fmaf(__uint_as_float(u0 << 16), w0, a0.x);
                a0.y = fmaf(__uint_as_float(u0 & 0xffff0000u), w0, a0.y);
                a1.x = fmaf(__uint_as_float(u1 << 16), w1, a1.x);
                a1.y = fmaf(__uint_as_float(u1 & 0xffff0000u), w1, a1.y);
                a2.x = fmaf(__uint_as_float(u2 << 16), w2v, a2.x);
                a2.y = fmaf(__uint_as_float(u2 & 0xffff0000u), w2v, a2.y);
                a3.x = fmaf(__uint_as_float(u3 << 16), w3, a3.x);
                a3.y = fmaf(__uint_as_float(u3 & 0xffff0000u), w3, a3.y);
            }
            for (; p < end; ++p) {
                const int s0 = csrc[p];
                const unsigned u0 = *(const unsigned*)&h1b[(size_t)s0 * 128 + lane * 2];
                const float w0 = dinv[s0] * dn;
                a0.x = fmaf(__uint_as_float(u0 << 16), w0, a0.x);
                a0.y = fmaf(__uint_as_float(u0 & 0xffff0000u), w0, a0.y);
            }
            vx = (a0.x + a1.x) + (a2.x + a3.x);
            vy = (a0.y + a1.y) + (a2.y + a3.y);
            // self-loop + bias + relu
            const unsigned su = *(const unsigned*)&h1b[(size_t)n * 128 + lane * 2];
            const float d2 = dn * dn;
            vx = fmaxf(fmaf(__uint_as_float(su << 16), d2, vx) + bb.x, 0.f);
            vy = fmaxf(fmaf(__uint_as_float(su & 0xffff0000u), d2, vy) + bb.y, 0.f);
        }
        *(float2*)&hs[nl][lane * 2] = make_float2(vx, vy);
    }
    __syncthreads();
    const int nn_ = t >> 3, j4 = (t & 7) * 4;
    const int node = n0 + nn_;
    float acc[4] = {0.f, 0.f, 0.f, 0.f};
    #pragma unroll 8
    for (int k = 0; k < 128; ++k) {
        const float hv = hs[nn_][k];
        const float4 wv = *(const float4*)&w2s[k * 32 + j4];
        acc[0] = fmaf(hv, wv.x, acc[0]);
        acc[1] = fmaf(hv, wv.y, acc[1]);
        acc[2] = fmaf(hv, wv.z, acc[2]);
        acc[3] = fmaf(hv, wv.w, acc[3]);
    }
    if (node < NN) {
        ushort4 pk;
        pk.x = f2b(acc[0]); pk.y = f2b(acc[1]);
        pk.z = f2b(acc[2]); pk.w = f2b(acc[3]);
        *(ushort4*)&hw2b[(size_t)node * 32 + j4] = pk;
    }
}

// 32 lanes per dst node: agg2[n][j] = sum_e hw2[src][j] * w
__global__ __launch_bounds__(256) void k_gather2(const int* __restrict__ rows,
                                                 const int* __restrict__ csrc,
                                                 const float* __restrict__ dinv,
                                                 const unsigned short* __restrict__ hw2b,
                                                 float* __restrict__ agg2) {
    const int n = (blockIdx.x * 256 + threadIdx.x) >> 5;
    const int j = threadIdx.x & 31;
    if (n >= NN) return;
    const int beg = rows[n], end = rows[n + 1];
    const float dn = dinv[n];
    float acc0 = 0.f, acc1 = 0.f;
    int p = beg;
    for (; p + 2 <= end; p += 2) {
        const int s0 = csrc[p], s1 = csrc[p + 1];
        const float w0 = dinv[s0] * dn, w1 = dinv[s1] * dn;
        acc0 = fmaf(b2f(hw2b[(size_t)s0 * 32 + j]), w0, acc0);
        acc1 = fmaf(b2f(hw2b[(size_t)s1 * 32 + j]), w1, acc1);
    }
    if (p < end) {
        const int s0 = csrc[p];
        acc0 = fmaf(b2f(hw2b[(size_t)s0 * 32 + j]), dinv[s0] * dn, acc0);
    }
    agg2[(size_t)n * 32 + j] = acc0 + acc1;
}

// out[r][j] = sum_n O[r][n] * (agg2[n][j] + hw2[n][j]/deg[n] + b2[j])
__global__ __launch_bounds__(256) void k_final(const float* __restrict__ O,
                                               const float* __restrict__ agg2,
                                               const unsigned short* __restrict__ hw2b,
                                               const float* __restrict__ dinv,
                                               const float* __restrict__ b2,
                                               float* __restrict__ out) {
    __shared__ float h2s[128][32];
    __shared__ float Os[64][128];
    const int t = threadIdx.x;
    const int n0 = blockIdx.x * 128;
    #pragma unroll
    for (int i = 0; i < 16; ++i) {
        const int idx = t + 256 * i;
        const int n = idx >> 5, j = idx & 31;
        const int node = n0 + n;
        float v = 0.f;
        if (node < NN) {
            float d2 = dinv[node];
            d2 *= d2;
            v = fmaf(b2f(hw2b[(size_t)node * 32 + j]), d2,
                     agg2[(size_t)node * 32 + j]) + b2[j];
        }
        h2s[n][j] = v;
    }
    #pragma unroll
    for (int i = 0; i < 32; ++i) {
        const int idx = t + 256 * i;
        const int r = idx >> 7, c = idx & 127;
        const int node = n0 + c;
        Os[r][c] = (node < NN) ? O[(size_t)r * NN + node] : 0.f;
    }
    __syncthreads();
    const int j = t & 31, k0 = (t >> 5) * 8;
    float acc[8];
    #pragma unroll
    for (int i = 0; i < 8; ++i) acc[i] = 0.f;
    for (int n = 0; n < 128; ++n) {
        const float hv = h2s[n][j];
        #pragma unroll
        for (int i = 0; i < 8; ++i) acc[i] = fmaf(Os[k0 + i][n], hv, acc[i]);
    }
    #pragma unroll
    for (int i = 0; i < 8; ++i) atomicAdd(&out[(k0 + i) * 32 + j], acc[i]);
}

extern "C" void kernel_launch(void* const* d_in, const int* in_sizes, int n_in,
                              void* d_out, int out_size, void* d_ws, size_t ws_size,
                              hipStream_t stream) {
    const float* x  = (const float*)d_in[0];
    const int*   ei = (const int*)d_in[1];
    const float* O  = (const float*)d_in[2];
    const float* W1 = (const float*)d_in[3];
    const float* b1 = (const float*)d_in[4];
    const float* W2 = (const float*)d_in[5];
    const float* b2 = (const float*)d_in[6];
    float* out = (float*)d_out;

    float* wsf = (float*)d_ws;
    unsigned short* h1b  = (unsigned short*)(wsf + OFF_H1);
    unsigned short* hw2b = (unsigned short*)(wsf + OFF_HW2);
    float*          agg2 = wsf + OFF_AGG2;
    float* dinv  = wsf + OFF_DINV;
    int*   rows  = (int*)(wsf + OFF_ROWS);
    int*   gcnt  = (int*)(wsf + OFF_GCNT);
    int*   gbase = (int*)(wsf + OFF_GBASE);
    int*   csrc  = (int*)(wsf + OFF_CSRC);
    uint2* binned = (uint2*)(wsf + OFF_BIN);

    hipMemsetAsync(gcnt, 0, NB * 4, stream);

    k_binA<<<256, 256, 0, stream>>>(ei, gcnt, binned);
    k_base<<<1, 128, 0, stream>>>(gcnt, gbase);
    k_binB<<<NB, 256, 0, stream>>>(gcnt, gbase, binned, rows, dinv, csrc);

    k_gemm1<<<dim3((NN + 63) / 64, 2), 256, 0, stream>>>(x, W1, h1b);
    k_gf1<<<(NN + 31) / 32, 256, 0, stream>>>(rows, csrc, dinv, h1b, b1, W2, hw2b);
    k_gather2<<<(NN * 32 + 255) / 256, 256, 0, stream>>>(rows, csrc, dinv, hw2b, agg2);

    hipMemsetAsync(out, 0, (size_t)out_size * 4, stream);
    k_final<<<(NN + 127) / 128, 256, 0, stream>>>(O, agg2, hw2b, dinv, b2, out);
}

// Round 2
// 273.123 us; speedup vs baseline: 1.2083x; 1.2083x over previous
//
#include <hip/hip_runtime.h>

#define NN 50000
#define NE 1600000
#define NB 98          // buckets = ceil(NN/512)
#define BSH 9          // bucket = dst >> 9
#define BCAP 17408     // per-bucket capacity: mean 16384 + 8 sigma

// workspace layout (units of 4B)
#define OFF_H1    0          // bf16 [NN][128] = 3.2M u
#define OFF_AGG1  3200000    // f32  [NN][128] = 6.4M u
#define OFF_HW2   9600000    // bf16 [NN][32]  = 0.8M u
#define OFF_AGG2  10400000   // f32  [NN][32]  = 1.6M u
#define OFF_DINV  12000000   // [NN] f32
#define OFF_ROWS  12050000   // [NN+1] int
#define OFF_GCNT  12101000   // [NB] int
#define OFF_GBASE 12101200   // [NB+1] int
#define OFF_CSRC  12102000   // [NE] int
#define OFF_BIN   13702000   // uint2[NB*BCAP] = 3,411,968 u
// total: 17,113,968 * 4B = 68.5 MB

__device__ __forceinline__ unsigned short f2b(float f) {
    unsigned u = __float_as_uint(f);
    u += 0x7fffu + ((u >> 16) & 1u);
    return (unsigned short)(u >> 16);
}
__device__ __forceinline__ float b2f(unsigned short h) {
    return __uint_as_float((unsigned)h << 16);
}
__device__ __forceinline__ float blo(unsigned u) { return __uint_as_float(u << 16); }
__device__ __forceinline__ float bhi(unsigned u) { return __uint_as_float(u & 0xffff0000u); }

// Pass A: bin edges into 98 dst-buckets. Per-edge atomics are LDS-only;
// one global atomic per block-bucket (25K total).
__global__ __launch_bounds__(256) void k_binA(const int* __restrict__ ei,
                                              int* __restrict__ gcount,
                                              uint2* __restrict__ binned) {
    __shared__ int hist[NB];
    const int t = threadIdx.x;
    if (t < NB) hist[t] = 0;
    __syncthreads();
    const int e0 = blockIdx.x * (NE / 256);      // 6250 edges/block, exact
    const int e1 = e0 + (NE / 256);
    for (int e = e0 + t; e < e1; e += 256)
        atomicAdd(&hist[ei[NE + e] >> BSH], 1);
    __syncthreads();
    if (t < NB) {
        const int v = hist[t];
        hist[t] = atomicAdd(&gcount[t], v);      // becomes global cursor
    }
    __syncthreads();
    for (int e = e0 + t; e < e1; e += 256) {
        const int s = ei[e], d = ei[NE + e];
        const int b = d >> BSH;
        const int pos = atomicAdd(&hist[b], 1);
        binned[(size_t)b * BCAP + pos] = make_uint2((unsigned)s, (unsigned)d);
    }
}

// exclusive scan of gcount[98] -> gbase
__global__ __launch_bounds__(128) void k_base(const int* __restrict__ gcount,
                                              int* __restrict__ gbase) {
    __shared__ int s[128];
    const int t = threadIdx.x;
    const int v = (t < NB) ? gcount[t] : 0;
    s[t] = v;
    __syncthreads();
    #pragma unroll
    for (int off = 1; off < 128; off <<= 1) {
        const int x = (t >= off) ? s[t - off] : 0;
        __syncthreads();
        s[t] += x;
        __syncthreads();
    }
    if (t < NB) gbase[t] = s[t] - v;
    if (t == NB - 1) gbase[NB] = s[t];
}

// Pass B: one block per bucket. Per-node degree (LDS hist) -> dinv, rows;
// LDS scan -> offsets; scatter csrc into block-exclusive 64KB window.
__global__ __launch_bounds__(256) void k_binB(const int* __restrict__ gcount,
                                              const int* __restrict__ gbase,
                                              const uint2* __restrict__ binned,
                                              int* __restrict__ rows,
                                              float* __restrict__ dinv,
                                              int* __restrict__ csrc) {
    __shared__ int deg[512];
    __shared__ int off[512];
    __shared__ int partial[256];
    const int b = blockIdx.x, t = threadIdx.x;
    const int n0 = b << BSH;
    const int nloc = (NN - n0 < 512) ? (NN - n0) : 512;
    const int cnt = gcount[b];
    const int obase = gbase[b];
    const uint2* eb = binned + (size_t)b * BCAP;
    deg[t] = 0;
    deg[t + 256] = 0;
    __syncthreads();
    for (int i = t; i < cnt; i += 256) atomicAdd(&deg[eb[i].y & 511], 1);
    __syncthreads();
    const int s0 = deg[2 * t], s1 = deg[2 * t + 1];
    partial[t] = s0 + s1;
    __syncthreads();
    #pragma unroll
    for (int o = 1; o < 256; o <<= 1) {
        const int x = (t >= o) ? partial[t - o] : 0;
        __syncthreads();
        partial[t] += x;
        __syncthreads();
    }
    const int ep = partial[t] - (s0 + s1);
    off[2 * t] = ep;
    off[2 * t + 1] = ep + s0;
    __syncthreads();
    for (int i = t; i < nloc; i += 256) {
        rows[n0 + i] = obase + off[i];
        dinv[n0 + i] = rsqrtf((float)deg[i] + 1.0f);
    }
    if (b == NB - 1 && t == 0) rows[NN] = NE;
    __syncthreads();                 // rows reads of off[] done before cursor reuse
    for (int i = t; i < cnt; i += 256) {
        const uint2 r = eb[i];
        const int local = atomicAdd(&off[r.y & 511], 1);
        csrc[obase + local] = (int)r.x;
    }
}

// h1[n][c] = sum_k x[k][n] * W1[k][c]; output bf16
__global__ __launch_bounds__(256) void k_gemm1(const float* __restrict__ x,
                                               const float* __restrict__ W1,
                                               unsigned short* __restrict__ h1b) {
    __shared__ float xs[128][64];
    __shared__ float wsh[128][64];
    const int t = threadIdx.x;
    const int n0 = blockIdx.x * 64, c0 = blockIdx.y * 64;
    {
        const int col = t & 63, r0 = t >> 6;
        #pragma unroll
        for (int i = 0; i < 32; ++i) {
            const int r = r0 + 4 * i;
            const int n = n0 + col;
            xs[r][col]  = (n < NN) ? x[(size_t)r * NN + n] : 0.f;
            wsh[r][col] = W1[r * 128 + c0 + col];
        }
    }
    __syncthreads();
    const int nr = (t & 15) * 4, cg = (t >> 4) * 4;
    float acc[4][4];
    #pragma unroll
    for (int i = 0; i < 4; ++i)
        #pragma unroll
        for (int j = 0; j < 4; ++j) acc[i][j] = 0.f;
    #pragma unroll 8
    for (int k = 0; k < 128; ++k) {
        const float4 xv = *(const float4*)&xs[k][nr];
        const float4 wv = *(const float4*)&wsh[k][cg];
        const float xa[4] = {xv.x, xv.y, xv.z, xv.w};
        const float wa[4] = {wv.x, wv.y, wv.z, wv.w};
        #pragma unroll
        for (int i = 0; i < 4; ++i)
            #pragma unroll
            for (int j = 0; j < 4; ++j) acc[i][j] = fmaf(xa[i], wa[j], acc[i][j]);
    }
    #pragma unroll
    for (int i = 0; i < 4; ++i) {
        const int n = n0 + nr + i;
        if (n < NN) {
            ushort4 pk;
            pk.x = f2b(acc[i][0]); pk.y = f2b(acc[i][1]);
            pk.z = f2b(acc[i][2]); pk.w = f2b(acc[i][3]);
            *(ushort4*)&h1b[(size_t)n * 128 + c0 + cg] = pk;
        }
    }
}

// one wave per dst node: agg1[n][:] = sum_e h1[src][:] * dinv[src]*dinv[n]
// v2: n forced wave-uniform via readfirstlane -> rows/dinv/csrc become
// scalar loads (s_load, lgkm pipe); 8 independent 256B row loads in flight
// per wave (4x the MLP of v1) with address math on SALU.
__global__ __launch_bounds__(256) void k_gather1(const int* __restrict__ rows,
                                                 const int* __restrict__ csrc,
                                                 const float* __restrict__ dinv,
                                                 const unsigned short* __restrict__ h1b,
                                                 float* __restrict__ agg1) {
    const int n = __builtin_amdgcn_readfirstlane((blockIdx.x * 256 + threadIdx.x) >> 6);
    const int lane = threadIdx.x & 63;
    if (n >= NN) return;
    const int beg = rows[n], end = rows[n + 1];
    const float dn = dinv[n];
    float ax0 = 0.f, ay0 = 0.f, ax1 = 0.f, ay1 = 0.f;
    int p = beg;
    for (; p + 8 <= end; p += 8) {
        const int s0 = csrc[p + 0], s1 = csrc[p + 1];
        const int s2 = csrc[p + 2], s3 = csrc[p + 3];
        const int s4 = csrc[p + 4], s5 = csrc[p + 5];
        const int s6 = csrc[p + 6], s7 = csrc[p + 7];
        const unsigned u0 = *(const unsigned*)&h1b[(size_t)s0 * 128 + lane * 2];
        const unsigned u1 = *(const unsigned*)&h1b[(size_t)s1 * 128 + lane * 2];
        const unsigned u2 = *(const unsigned*)&h1b[(size_t)s2 * 128 + lane * 2];
        const unsigned u3 = *(const unsigned*)&h1b[(size_t)s3 * 128 + lane * 2];
        const unsigned u4 = *(const unsigned*)&h1b[(size_t)s4 * 128 + lane * 2];
        const unsigned u5 = *(const unsigned*)&h1b[(size_t)s5 * 128 + lane * 2];
        const unsigned u6 = *(const unsigned*)&h1b[(size_t)s6 * 128 + lane * 2];
        const unsigned u7 = *(const unsigned*)&h1b[(size_t)s7 * 128 + lane * 2];
        const float w0 = dinv[s0] * dn, w1 = dinv[s1] * dn;
        const float w2 = dinv[s2] * dn, w3 = dinv[s3] * dn;
        const float w4 = dinv[s4] * dn, w5 = dinv[s5] * dn;
        const float w6 = dinv[s6] * dn, w7 = dinv[s7] * dn;
        ax0 = fmaf(blo(u0), w0, ax0); ay0 = fmaf(bhi(u0), w0, ay0);
        ax1 = fmaf(blo(u1), w1, ax1); ay1 = fmaf(bhi(u1), w1, ay1);
        ax0 = fmaf(blo(u2), w2, ax0); ay0 = fmaf(bhi(u2), w2, ay0);
        ax1 = fmaf(blo(u3), w3, ax1); ay1 = fmaf(bhi(u3), w3, ay1);
        ax0 = fmaf(blo(u4), w4, ax0); ay0 = fmaf(bhi(u4), w4, ay0);
        ax1 = fmaf(blo(u5), w5, ax1); ay1 = fmaf(bhi(u5), w5, ay1);
        ax0 = fmaf(blo(u6), w6, ax0); ay0 = fmaf(bhi(u6), w6, ay0);
        ax1 = fmaf(blo(u7), w7, ax1); ay1 = fmaf(bhi(u7), w7, ay1);
    }
    if (p + 4 <= end) {
        const int s0 = csrc[p + 0], s1 = csrc[p + 1];
        const int s2 = csrc[p + 2], s3 = csrc[p + 3];
        const unsigned u0 = *(const unsigned*)&h1b[(size_t)s0 * 128 + lane * 2];
        const unsigned u1 = *(const unsigned*)&h1b[(size_t)s1 * 128 + lane * 2];
        const unsigned u2 = *(const unsigned*)&h1b[(size_t)s2 * 128 + lane * 2];
        const unsigned u3 = *(const unsigned*)&h1b[(size_t)s3 * 128 + lane * 2];
        const float w0 = dinv[s0] * dn, w1 = dinv[s1] * dn;
        const float w2 = dinv[s2] * dn, w3 = dinv[s3] * dn;
        ax0 = fmaf(blo(u0), w0, ax0); ay0 = fmaf(bhi(u0), w0, ay0);
        ax1 = fmaf(blo(u1), w1, ax1); ay1 = fmaf(bhi(u1), w1, ay1);
        ax0 = fmaf(blo(u2), w2, ax0); ay0 = fmaf(bhi(u2), w2, ay0);
        ax1 = fmaf(blo(u3), w3, ax1); ay1 = fmaf(bhi(u3), w3, ay1);
        p += 4;
    }
    for (; p < end; ++p) {
        const int s0 = csrc[p];
        const unsigned u0 = *(const unsigned*)&h1b[(size_t)s0 * 128 + lane * 2];
        const float w0 = dinv[s0] * dn;
        ax0 = fmaf(blo(u0), w0, ax0); ay0 = fmaf(bhi(u0), w0, ay0);
    }
    *(float2*)&agg1[(size_t)n * 128 + lane * 2] = make_float2(ax0 + ax1, ay0 + ay1);
}

// h1r = relu(agg1 + h1/deg + b1) -> LDS; hw2 = h1r @ W2 (bf16 out)
__global__ __launch_bounds__(256) void k_fuse1(const float* __restrict__ agg1,
                                               const unsigned short* __restrict__ h1b,
                                               const float* __restrict__ dinv,
                                               const float* __restrict__ b1,
                                               const float* __restrict__ W2,
                                               unsigned short* __restrict__ hw2b) {
    __shared__ float hs[32][132];
    __shared__ float w2s[128 * 32];
    const int t = threadIdx.x;
    const int n0 = blockIdx.x * 32;
    #pragma unroll
    for (int i = 0; i < 16; ++i) w2s[t + 256 * i] = W2[t + 256 * i];
    #pragma unroll
    for (int i = 0; i < 4; ++i) {
        const int idx4 = t + 256 * i;
        const int n = idx4 >> 5, c4 = (idx4 & 31) * 4;
        const int node = n0 + n;
        float4 r = make_float4(0.f, 0.f, 0.f, 0.f);
        if (node < NN) {
            const float4 a = *(const float4*)&agg1[(size_t)node * 128 + c4];
            const ushort4 hu = *(const ushort4*)&h1b[(size_t)node * 128 + c4];
            float d2 = dinv[node];
            d2 *= d2;
            const float4 bb = *(const float4*)&b1[c4];
            r.x = fmaxf(fmaf(b2f(hu.x), d2, a.x) + bb.x, 0.f);
            r.y = fmaxf(fmaf(b2f(hu.y), d2, a.y) + bb.y, 0.f);
            r.z = fmaxf(fmaf(b2f(hu.z), d2, a.z) + bb.z, 0.f);
            r.w = fmaxf(fmaf(b2f(hu.w), d2, a.w) + bb.w, 0.f);
        }
        *(float4*)&hs[n][c4] = r;
    }
    __syncthreads();
    const int n = t >> 3, j4 = (t & 7) * 4;
    const int node = n0 + n;
    float acc[4] = {0.f, 0.f, 0.f, 0.f};
    #pragma unroll 8
    for (int k = 0; k < 128; ++k) {
        const float hv = hs[n][k];
        const float4 wv = *(const float4*)&w2s[k * 32 + j4];
        acc[0] = fmaf(hv, wv.x, acc[0]);
        acc[1] = fmaf(hv, wv.y, acc[1]);
        acc[2] = fmaf(hv, wv.z, acc[2]);
        acc[3] = fmaf(hv, wv.w, acc[3]);
    }
    if (node < NN) {
        ushort4 pk;
        pk.x = f2b(acc[0]); pk.y = f2b(acc[1]);
        pk.z = f2b(acc[2]); pk.w = f2b(acc[3]);
        *(ushort4*)&hw2b[(size_t)node * 32 + j4] = pk;
    }
}

// 32 lanes per dst node: agg2[n][j] = sum_e hw2[src][j] * w
__global__ __launch_bounds__(256) void k_gather2(const int* __restrict__ rows,
                                                 const int* __restrict__ csrc,
                                                 const float* __restrict__ dinv,
                                                 const unsigned short* __restrict__ hw2b,
                                                 float* __restrict__ agg2) {
    const int n = (blockIdx.x * 256 + threadIdx.x) >> 5;
    const int j = threadIdx.x & 31;
    if (n >= NN) return;
    const int beg = rows[n], end = rows[n + 1];
    const float dn = dinv[n];
    float acc0 = 0.f, acc1 = 0.f;
    int p = beg;
    for (; p + 2 <= end; p += 2) {
        const int s0 = csrc[p], s1 = csrc[p + 1];
        const float w0 = dinv[s0] * dn, w1 = dinv[s1] * dn;
        acc0 = fmaf(b2f(hw2b[(size_t)s0 * 32 + j]), w0, acc0);
        acc1 = fmaf(b2f(hw2b[(size_t)s1 * 32 + j]), w1, acc1);
    }
    if (p < end) {
        const int s0 = csrc[p];
        acc0 = fmaf(b2f(hw2b[(size_t)s0 * 32 + j]), dinv[s0] * dn, acc0);
    }
    agg2[(size_t)n * 32 + j] = acc0 + acc1;
}

// out[r][j] = sum_n O[r][n] * (agg2[n][j] + hw2[n][j]/deg[n] + b2[j])
__global__ __launch_bounds__(256) void k_final(const float* __restrict__ O,
                                               const float* __restrict__ agg2,
                                               const unsigned short* __restrict__ hw2b,
                                               const float* __restrict__ dinv,
                                               const float* __restrict__ b2,
                                               float* __restrict__ out) {
    __shared__ float h2s[128][32];
    __shared__ float Os[64][128];
    const int t = threadIdx.x;
    const int n0 = blockIdx.x * 128;
    #pragma unroll
    for (int i = 0; i < 16; ++i) {
        const int idx = t + 256 * i;
        const int n = idx >> 5, j = idx & 31;
        const int node = n0 + n;
        float v = 0.f;
        if (node < NN) {
            float d2 = dinv[node];
            d2 *= d2;
            v = fmaf(b2f(hw2b[(size_t)node * 32 + j]), d2,
                     agg2[(size_t)node * 32 + j]) + b2[j];
        }
        h2s[n][j] = v;
    }
    #pragma unroll
    for (int i = 0; i < 32; ++i) {
        const int idx = t + 256 * i;
        const int r = idx >> 7, c = idx & 127;
        const int node = n0 + c;
        Os[r][c] = (node < NN) ? O[(size_t)r * NN + node] : 0.f;
    }
    __syncthreads();
    const int j = t & 31, k0 = (t >> 5) * 8;
    float acc[8];
    #pragma unroll
    for (int i = 0; i < 8; ++i) acc[i] = 0.f;
    for (int n = 0; n < 128; ++n) {
        const float hv = h2s[n][j];
        #pragma unroll
        for (int i = 0; i < 8; ++i) acc[i] = fmaf(Os[k0 + i][n], hv, acc[i]);
    }
    #pragma unroll
    for (int i = 0; i < 8; ++i) atomicAdd(&out[(k0 + i) * 32 + j], acc[i]);
}

extern "C" void kernel_launch(void* const* d_in, const int* in_sizes, int n_in,
                              void* d_out, int out_size, void* d_ws, size_t ws_size,
                              hipStream_t stream) {
    const float* x  = (const float*)d_in[0];
    const int*   ei = (const int*)d_in[1];
    const float* O  = (const float*)d_in[2];
    const float* W1 = (const float*)d_in[3];
    const float* b1 = (const float*)d_in[4];
    const float* W2 = (const float*)d_in[5];
    const float* b2 = (const float*)d_in[6];
    float* out = (float*)d_out;

    float* wsf = (float*)d_ws;
    unsigned short* h1b  = (unsigned short*)(wsf + OFF_H1);
    float*          agg1 = wsf + OFF_AGG1;
    unsigned short* hw2b = (unsigned short*)(wsf + OFF_HW2);
    float*          agg2 = wsf + OFF_AGG2;
    float* dinv  = wsf + OFF_DINV;
    int*   rows  = (int*)(wsf + OFF_ROWS);
    int*   gcnt  = (int*)(wsf + OFF_GCNT);
    int*   gbase = (int*)(wsf + OFF_GBASE);
    int*   csrc  = (int*)(wsf + OFF_CSRC);
    uint2* binned = (uint2*)(wsf + OFF_BIN);

    hipMemsetAsync(gcnt, 0, NB * 4, stream);

    k_binA<<<256, 256, 0, stream>>>(ei, gcnt, binned);
    k_base<<<1, 128, 0, stream>>>(gcnt, gbase);
    k_binB<<<NB, 256, 0, stream>>>(gcnt, gbase, binned, rows, dinv, csrc);

    k_gemm1<<<dim3((NN + 63) / 64, 2), 256, 0, stream>>>(x, W1, h1b);
    k_gather1<<<(NN * 64 + 255) / 256, 256, 0, stream>>>(rows, csrc, dinv, h1b, agg1);
    k_fuse1<<<(NN + 31) / 32, 256, 0, stream>>>(agg1, h1b, dinv, b1, W2, hw2b);
    k_gather2<<<(NN * 32 + 255) / 256, 256, 0, stream>>>(rows, csrc, dinv, hw2b, agg2);

    hipMemsetAsync(out, 0, (size_t)out_size * 4, stream);
    k_final<<<(NN + 127) / 128, 256, 0, stream>>>(O, agg2, hw2b, dinv, b2, out);
}

// Round 3
// 254.577 us; speedup vs baseline: 1.2963x; 1.0728x over previous
//
#include <hip/hip_runtime.h>

#define NN 50000
#define NE 1600000
#define NB 98          // buckets = ceil(NN/512)
#define BSH 9          // bucket = dst >> 9
#define BCAP 17408     // per-bucket capacity: mean 16384 + 8 sigma

// workspace layout (units of 4B)
#define OFF_H1    0          // bf16 [NN][128] = 3.2M u
#define OFF_AGG1  3200000    // f32  [NN][128] = 6.4M u
#define OFF_HW2   9600000    // bf16 [NN][32]  = 0.8M u
#define OFF_AGG2  10400000   // f32  [NN][32]  = 1.6M u
#define OFF_DINV  12000000   // [NN] f32
#define OFF_ROWS  12050000   // [NN+1] int
#define OFF_GCNT  12101000   // [NB] int
#define OFF_GBASE 12101200   // [NB+1] int
#define OFF_CSRC  12102000   // [NE] int
#define OFF_BIN   13702000   // uint2[NB*BCAP] = 3,411,968 u  (dead after k_binB;
                             //  w1t bf16[128][128] aliases its head)
// total: 17,113,968 * 4B = 68.5 MB

typedef __attribute__((ext_vector_type(8))) short bf16x8;
typedef __attribute__((ext_vector_type(8))) unsigned short u16x8;
typedef __attribute__((ext_vector_type(4))) float f32x4;

__device__ __forceinline__ unsigned short f2b(float f) {
    unsigned u = __float_as_uint(f);
    u += 0x7fffu + ((u >> 16) & 1u);
    return (unsigned short)(u >> 16);
}
__device__ __forceinline__ float b2f(unsigned short h) {
    return __uint_as_float((unsigned)h << 16);
}
__device__ __forceinline__ float blo(unsigned u) { return __uint_as_float(u << 16); }
__device__ __forceinline__ float bhi(unsigned u) { return __uint_as_float(u & 0xffff0000u); }

// Pass A: bin edges into 98 dst-buckets. Per-edge atomics are LDS-only;
// one global atomic per block-bucket (25K total).
__global__ __launch_bounds__(256) void k_binA(const int* __restrict__ ei,
                                              int* __restrict__ gcount,
                                              uint2* __restrict__ binned) {
    __shared__ int hist[NB];
    const int t = threadIdx.x;
    if (t < NB) hist[t] = 0;
    __syncthreads();
    const int e0 = blockIdx.x * (NE / 256);      // 6250 edges/block, exact
    const int e1 = e0 + (NE / 256);
    for (int e = e0 + t; e < e1; e += 256)
        atomicAdd(&hist[ei[NE + e] >> BSH], 1);
    __syncthreads();
    if (t < NB) {
        const int v = hist[t];
        hist[t] = atomicAdd(&gcount[t], v);      // becomes global cursor
    }
    __syncthreads();
    for (int e = e0 + t; e < e1; e += 256) {
        const int s = ei[e], d = ei[NE + e];
        const int b = d >> BSH;
        const int pos = atomicAdd(&hist[b], 1);
        binned[(size_t)b * BCAP + pos] = make_uint2((unsigned)s, (unsigned)d);
    }
}

// exclusive scan of gcount[98] -> gbase
__global__ __launch_bounds__(128) void k_base(const int* __restrict__ gcount,
                                              int* __restrict__ gbase) {
    __shared__ int s[128];
    const int t = threadIdx.x;
    const int v = (t < NB) ? gcount[t] : 0;
    s[t] = v;
    __syncthreads();
    #pragma unroll
    for (int off = 1; off < 128; off <<= 1) {
        const int x = (t >= off) ? s[t - off] : 0;
        __syncthreads();
        s[t] += x;
        __syncthreads();
    }
    if (t < NB) gbase[t] = s[t] - v;
    if (t == NB - 1) gbase[NB] = s[t];
}

// Pass B: one block per bucket. Per-node degree (LDS hist) -> dinv, rows;
// LDS scan -> offsets; scatter csrc into block-exclusive 64KB window.
__global__ __launch_bounds__(256) void k_binB(const int* __restrict__ gcount,
                                              const int* __restrict__ gbase,
                                              const uint2* __restrict__ binned,
                                              int* __restrict__ rows,
                                              float* __restrict__ dinv,
                                              int* __restrict__ csrc) {
    __shared__ int deg[512];
    __shared__ int off[512];
    __shared__ int partial[256];
    const int b = blockIdx.x, t = threadIdx.x;
    const int n0 = b << BSH;
    const int nloc = (NN - n0 < 512) ? (NN - n0) : 512;
    const int cnt = gcount[b];
    const int obase = gbase[b];
    const uint2* eb = binned + (size_t)b * BCAP;
    deg[t] = 0;
    deg[t + 256] = 0;
    __syncthreads();
    for (int i = t; i < cnt; i += 256) atomicAdd(&deg[eb[i].y & 511], 1);
    __syncthreads();
    const int s0 = deg[2 * t], s1 = deg[2 * t + 1];
    partial[t] = s0 + s1;
    __syncthreads();
    #pragma unroll
    for (int o = 1; o < 256; o <<= 1) {
        const int x = (t >= o) ? partial[t - o] : 0;
        __syncthreads();
        partial[t] += x;
        __syncthreads();
    }
    const int ep = partial[t] - (s0 + s1);
    off[2 * t] = ep;
    off[2 * t + 1] = ep + s0;
    __syncthreads();
    for (int i = t; i < nloc; i += 256) {
        rows[n0 + i] = obase + off[i];
        dinv[n0 + i] = rsqrtf((float)deg[i] + 1.0f);
    }
    if (b == NB - 1 && t == 0) rows[NN] = NE;
    __syncthreads();                 // rows reads of off[] done before cursor reuse
    for (int i = t; i < cnt; i += 256) {
        const uint2 r = eb[i];
        const int local = atomicAdd(&off[r.y & 511], 1);
        csrc[obase + local] = (int)r.x;
    }
}

// W1[k][c] f32 -> w1t[c][k] bf16 (runs after k_binB; w1t aliases binned)
__global__ __launch_bounds__(256) void k_w1t(const float* __restrict__ W1,
                                             unsigned short* __restrict__ w1t) {
    const int t = threadIdx.x;
    #pragma unroll
    for (int i = 0; i < 64; ++i) {
        const int id = t + 256 * i;          // coalesced read of W1
        const int k = id >> 7, c = id & 127;
        w1t[c * 128 + k] = f2b(W1[id]);
    }
}

// MFMA GEMM: h1[n][c] = sum_k xT[n][k] * W1[k][c], bf16 inputs, f32 accum.
// Block: 4 waves, 64 nodes x 128 cols. LDS: x-tile [64][136] bf16 (transposed
// during staging), W-tile [128][136] bf16 from pre-transposed w1t.
// +8 pad -> row stride 68 words -> b128 frag reads at the 8-cycle floor.
__global__ __launch_bounds__(256) void k_gemm1(const float* __restrict__ x,
                                               const unsigned short* __restrict__ w1t,
                                               unsigned short* __restrict__ h1b) {
    __shared__ unsigned short lxs[64 * 136];
    __shared__ unsigned short lws[128 * 136];
    const int t = threadIdx.x;
    const int gn0 = blockIdx.x * 64;
    // stage W: 2048 ushort8 chunks (vector copy, no convert)
    #pragma unroll
    for (int i = 0; i < 8; ++i) {
        const int id = t + 256 * i;          // 0..2047
        const int c = id >> 4, k8 = (id & 15) * 8;
        *(u16x8*)&lws[c * 136 + k8] = *(const u16x8*)&w1t[c * 128 + k8];
    }
    // stage x: coalesced f32 rows, convert, transposed LDS write
    {
        const int col = t & 63, kr = t >> 6;
        const int gn = gn0 + col;
        #pragma unroll
        for (int i = 0; i < 32; ++i) {
            const int k = kr * 32 + i;
            const float v = (gn < NN) ? x[(size_t)k * NN + gn] : 0.f;
            lxs[col * 136 + k] = f2b(v);
        }
    }
    __syncthreads();
    const int w = t >> 6, l = t & 63;
    const int lr = l & 15, lg = l >> 4;      // lg = 0..3
    const unsigned short* pa = &lxs[(w * 16 + lr) * 136 + lg * 8];
    const unsigned short* pb = &lws[lr * 136 + lg * 8];
    f32x4 acc[8];
    #pragma unroll
    for (int ct = 0; ct < 8; ++ct) acc[ct] = (f32x4){0.f, 0.f, 0.f, 0.f};
    #pragma unroll
    for (int ks = 0; ks < 4; ++ks) {
        const bf16x8 av = *(const bf16x8*)&pa[ks * 32];
        #pragma unroll
        for (int ct = 0; ct < 8; ++ct) {
            const bf16x8 bv = *(const bf16x8*)&pb[ct * 16 * 136 + ks * 32];
            acc[ct] = __builtin_amdgcn_mfma_f32_16x16x32_bf16(av, bv, acc[ct], 0, 0, 0);
        }
    }
    // C/D layout: col = lane&15, row = (lane>>4)*4 + reg  [m89-verified]
    const int nl0 = w * 16 + lg * 4;
    #pragma unroll
    for (int ct = 0; ct < 8; ++ct) {
        const int c = ct * 16 + lr;
        #pragma unroll
        for (int r = 0; r < 4; ++r) {
            const int gn = gn0 + nl0 + r;
            if (gn < NN) h1b[(size_t)gn * 128 + c] = f2b(acc[ct][r]);
        }
    }
}

// one wave per dst node: agg1[n][:] = sum_e h1[src][:] * dinv[src]*dinv[n]
// n wave-uniform via readfirstlane -> rows/dinv/csrc become scalar loads;
// 8 independent 256B row loads in flight per wave.
__global__ __launch_bounds__(256) void k_gather1(const int* __restrict__ rows,
                                                 const int* __restrict__ csrc,
                                                 const float* __restrict__ dinv,
                                                 const unsigned short* __restrict__ h1b,
                                                 float* __restrict__ agg1) {
    const int n = __builtin_amdgcn_readfirstlane((blockIdx.x * 256 + threadIdx.x) >> 6);
    const int lane = threadIdx.x & 63;
    if (n >= NN) return;
    const int beg = rows[n], end = rows[n + 1];
    const float dn = dinv[n];
    float ax0 = 0.f, ay0 = 0.f, ax1 = 0.f, ay1 = 0.f;
    int p = beg;
    for (; p + 8 <= end; p += 8) {
        const int s0 = csrc[p + 0], s1 = csrc[p + 1];
        const int s2 = csrc[p + 2], s3 = csrc[p + 3];
        const int s4 = csrc[p + 4], s5 = csrc[p + 5];
        const int s6 = csrc[p + 6], s7 = csrc[p + 7];
        const unsigned u0 = *(const unsigned*)&h1b[(size_t)s0 * 128 + lane * 2];
        const unsigned u1 = *(const unsigned*)&h1b[(size_t)s1 * 128 + lane * 2];
        const unsigned u2 = *(const unsigned*)&h1b[(size_t)s2 * 128 + lane * 2];
        const unsigned u3 = *(const unsigned*)&h1b[(size_t)s3 * 128 + lane * 2];
        const unsigned u4 = *(const unsigned*)&h1b[(size_t)s4 * 128 + lane * 2];
        const unsigned u5 = *(const unsigned*)&h1b[(size_t)s5 * 128 + lane * 2];
        const unsigned u6 = *(const unsigned*)&h1b[(size_t)s6 * 128 + lane * 2];
        const unsigned u7 = *(const unsigned*)&h1b[(size_t)s7 * 128 + lane * 2];
        const float w0 = dinv[s0] * dn, w1 = dinv[s1] * dn;
        const float w2 = dinv[s2] * dn, w3 = dinv[s3] * dn;
        const float w4 = dinv[s4] * dn, w5 = dinv[s5] * dn;
        const float w6 = dinv[s6] * dn, w7 = dinv[s7] * dn;
        ax0 = fmaf(blo(u0), w0, ax0); ay0 = fmaf(bhi(u0), w0, ay0);
        ax1 = fmaf(blo(u1), w1, ax1); ay1 = fmaf(bhi(u1), w1, ay1);
        ax0 = fmaf(blo(u2), w2, ax0); ay0 = fmaf(bhi(u2), w2, ay0);
        ax1 = fmaf(blo(u3), w3, ax1); ay1 = fmaf(bhi(u3), w3, ay1);
        ax0 = fmaf(blo(u4), w4, ax0); ay0 = fmaf(bhi(u4), w4, ay0);
        ax1 = fmaf(blo(u5), w5, ax1); ay1 = fmaf(bhi(u5), w5, ay1);
        ax0 = fmaf(blo(u6), w6, ax0); ay0 = fmaf(bhi(u6), w6, ay0);
        ax1 = fmaf(blo(u7), w7, ax1); ay1 = fmaf(bhi(u7), w7, ay1);
    }
    if (p + 4 <= end) {
        const int s0 = csrc[p + 0], s1 = csrc[p + 1];
        const int s2 = csrc[p + 2], s3 = csrc[p + 3];
        const unsigned u0 = *(const unsigned*)&h1b[(size_t)s0 * 128 + lane * 2];
        const unsigned u1 = *(const unsigned*)&h1b[(size_t)s1 * 128 + lane * 2];
        const unsigned u2 = *(const unsigned*)&h1b[(size_t)s2 * 128 + lane * 2];
        const unsigned u3 = *(const unsigned*)&h1b[(size_t)s3 * 128 + lane * 2];
        const float w0 = dinv[s0] * dn, w1 = dinv[s1] * dn;
        const float w2 = dinv[s2] * dn, w3 = dinv[s3] * dn;
        ax0 = fmaf(blo(u0), w0, ax0); ay0 = fmaf(bhi(u0), w0, ay0);
        ax1 = fmaf(blo(u1), w1, ax1); ay1 = fmaf(bhi(u1), w1, ay1);
        ax0 = fmaf(blo(u2), w2, ax0); ay0 = fmaf(bhi(u2), w2, ay0);
        ax1 = fmaf(blo(u3), w3, ax1); ay1 = fmaf(bhi(u3), w3, ay1);
        p += 4;
    }
    for (; p < end; ++p) {
        const int s0 = csrc[p];
        const unsigned u0 = *(const unsigned*)&h1b[(size_t)s0 * 128 + lane * 2];
        const float w0 = dinv[s0] * dn;
        ax0 = fmaf(blo(u0), w0, ax0); ay0 = fmaf(bhi(u0), w0, ay0);
    }
    *(float2*)&agg1[(size_t)n * 128 + lane * 2] = make_float2(ax0 + ax1, ay0 + ay1);
}

// h1r = relu(agg1 + h1/deg + b1) -> LDS; hw2 = h1r @ W2 (bf16 out)
__global__ __launch_bounds__(256) void k_fuse1(const float* __restrict__ agg1,
                                               const unsigned short* __restrict__ h1b,
                                               const float* __restrict__ dinv,
                                               const float* __restrict__ b1,
                                               const float* __restrict__ W2,
                                               unsigned short* __restrict__ hw2b) {
    __shared__ float hs[32][132];
    __shared__ float w2s[128 * 32];
    const int t = threadIdx.x;
    const int n0 = blockIdx.x * 32;
    #pragma unroll
    for (int i = 0; i < 16; ++i) w2s[t + 256 * i] = W2[t + 256 * i];
    #pragma unroll
    for (int i = 0; i < 4; ++i) {
        const int idx4 = t + 256 * i;
        const int n = idx4 >> 5, c4 = (idx4 & 31) * 4;
        const int node = n0 + n;
        float4 r = make_float4(0.f, 0.f, 0.f, 0.f);
        if (node < NN) {
            const float4 a = *(const float4*)&agg1[(size_t)node * 128 + c4];
            const ushort4 hu = *(const ushort4*)&h1b[(size_t)node * 128 + c4];
            float d2 = dinv[node];
            d2 *= d2;
            const float4 bb = *(const float4*)&b1[c4];
            r.x = fmaxf(fmaf(b2f(hu.x), d2, a.x) + bb.x, 0.f);
            r.y = fmaxf(fmaf(b2f(hu.y), d2, a.y) + bb.y, 0.f);
            r.z = fmaxf(fmaf(b2f(hu.z), d2, a.z) + bb.z, 0.f);
            r.w = fmaxf(fmaf(b2f(hu.w), d2, a.w) + bb.w, 0.f);
        }
        *(float4*)&hs[n][c4] = r;
    }
    __syncthreads();
    const int n = t >> 3, j4 = (t & 7) * 4;
    const int node = n0 + n;
    float acc[4] = {0.f, 0.f, 0.f, 0.f};
    #pragma unroll 8
    for (int k = 0; k < 128; ++k) {
        const float hv = hs[n][k];
        const float4 wv = *(const float4*)&w2s[k * 32 + j4];
        acc[0] = fmaf(hv, wv.x, acc[0]);
        acc[1] = fmaf(hv, wv.y, acc[1]);
        acc[2] = fmaf(hv, wv.z, acc[2]);
        acc[3] = fmaf(hv, wv.w, acc[3]);
    }
    if (node < NN) {
        ushort4 pk;
        pk.x = f2b(acc[0]); pk.y = f2b(acc[1]);
        pk.z = f2b(acc[2]); pk.w = f2b(acc[3]);
        *(ushort4*)&hw2b[(size_t)node * 32 + j4] = pk;
    }
}

// 32 lanes per dst node: agg2[n][j] = sum_e hw2[src][j] * w
__global__ __launch_bounds__(256) void k_gather2(const int* __restrict__ rows,
                                                 const int* __restrict__ csrc,
                                                 const float* __restrict__ dinv,
                                                 const unsigned short* __restrict__ hw2b,
                                                 float* __restrict__ agg2) {
    const int n = (blockIdx.x * 256 + threadIdx.x) >> 5;
    const int j = threadIdx.x & 31;
    if (n >= NN) return;
    const int beg = rows[n], end = rows[n + 1];
    const float dn = dinv[n];
    float acc0 = 0.f, acc1 = 0.f;
    int p = beg;
    for (; p + 2 <= end; p += 2) {
        const int s0 = csrc[p], s1 = csrc[p + 1];
        const float w0 = dinv[s0] * dn, w1 = dinv[s1] * dn;
        acc0 = fmaf(b2f(hw2b[(size_t)s0 * 32 + j]), w0, acc0);
        acc1 = fmaf(b2f(hw2b[(size_t)s1 * 32 + j]), w1, acc1);
    }
    if (p < end) {
        const int s0 = csrc[p];
        acc0 = fmaf(b2f(hw2b[(size_t)s0 * 32 + j]), dinv[s0] * dn, acc0);
    }
    agg2[(size_t)n * 32 + j] = acc0 + acc1;
}

// out[r][j] = sum_n O[r][n] * (agg2[n][j] + hw2[n][j]/deg[n] + b2[j])
__global__ __launch_bounds__(256) void k_final(const float* __restrict__ O,
                                               const float* __restrict__ agg2,
                                               const unsigned short* __restrict__ hw2b,
                                               const float* __restrict__ dinv,
                                               const float* __restrict__ b2,
                                               float* __restrict__ out) {
    __shared__ float h2s[128][32];
    __shared__ float Os[64][128];
    const int t = threadIdx.x;
    const int n0 = blockIdx.x * 128;
    #pragma unroll
    for (int i = 0; i < 16; ++i) {
        const int idx = t + 256 * i;
        const int n = idx >> 5, j = idx & 31;
        const int node = n0 + n;
        float v = 0.f;
        if (node < NN) {
            float d2 = dinv[node];
            d2 *= d2;
            v = fmaf(b2f(hw2b[(size_t)node * 32 + j]), d2,
                     agg2[(size_t)node * 32 + j]) + b2[j];
        }
        h2s[n][j] = v;
    }
    #pragma unroll
    for (int i = 0; i < 32; ++i) {
        const int idx = t + 256 * i;
        const int r = idx >> 7, c = idx & 127;
        const int node = n0 + c;
        Os[r][c] = (node < NN) ? O[(size_t)r * NN + node] : 0.f;
    }
    __syncthreads();
    const int j = t & 31, k0 = (t >> 5) * 8;
    float acc[8];
    #pragma unroll
    for (int i = 0; i < 8; ++i) acc[i] = 0.f;
    for (int n = 0; n < 128; ++n) {
        const float hv = h2s[n][j];
        #pragma unroll
        for (int i = 0; i < 8; ++i) acc[i] = fmaf(Os[k0 + i][n], hv, acc[i]);
    }
    #pragma unroll
    for (int i = 0; i < 8; ++i) atomicAdd(&out[(k0 + i) * 32 + j], acc[i]);
}

extern "C" void kernel_launch(void* const* d_in, const int* in_sizes, int n_in,
                              void* d_out, int out_size, void* d_ws, size_t ws_size,
                              hipStream_t stream) {
    const float* x  = (const float*)d_in[0];
    const int*   ei = (const int*)d_in[1];
    const float* O  = (const float*)d_in[2];
    const float* W1 = (const float*)d_in[3];
    const float* b1 = (const float*)d_in[4];
    const float* W2 = (const float*)d_in[5];
    const float* b2 = (const float*)d_in[6];
    float* out = (float*)d_out;

    float* wsf = (float*)d_ws;
    unsigned short* h1b  = (unsigned short*)(wsf + OFF_H1);
    float*          agg1 = wsf + OFF_AGG1;
    unsigned short* hw2b = (unsigned short*)(wsf + OFF_HW2);
    float*          agg2 = wsf + OFF_AGG2;
    float* dinv  = wsf + OFF_DINV;
    int*   rows  = (int*)(wsf + OFF_ROWS);
    int*   gcnt  = (int*)(wsf + OFF_GCNT);
    int*   gbase = (int*)(wsf + OFF_GBASE);
    int*   csrc  = (int*)(wsf + OFF_CSRC);
    uint2* binned = (uint2*)(wsf + OFF_BIN);
    unsigned short* w1t = (unsigned short*)(wsf + OFF_BIN);  // aliases dead binned

    hipMemsetAsync(gcnt, 0, NB * 4, stream);

    k_binA<<<256, 256, 0, stream>>>(ei, gcnt, binned);
    k_base<<<1, 128, 0, stream>>>(gcnt, gbase);
    k_binB<<<NB, 256, 0, stream>>>(gcnt, gbase, binned, rows, dinv, csrc);

    k_w1t<<<1, 256, 0, stream>>>(W1, w1t);
    k_gemm1<<<(NN + 63) / 64, 256, 0, stream>>>(x, w1t, h1b);
    k_gather1<<<(NN * 64 + 255) / 256, 256, 0, stream>>>(rows, csrc, dinv, h1b, agg1);
    k_fuse1<<<(NN + 31) / 32, 256, 0, stream>>>(agg1, h1b, dinv, b1, W2, hw2b);
    k_gather2<<<(NN * 32 + 255) / 256, 256, 0, stream>>>(rows, csrc, dinv, hw2b, agg2);

    hipMemsetAsync(out, 0, (size_t)out_size * 4, stream);
    k_final<<<(NN + 127) / 128, 256, 0, stream>>>(O, agg2, hw2b, dinv, b2, out);
}